// Round 5
// baseline (258.113 us; speedup 1.0000x reference)
//
#include <hip/hip_runtime.h>

#define S_   2048
#define D_   1024
#define H_   16
#define HD_  64
#define NTOK 8192   // B*S
#define QKS  2048   // row stride of fused QK output
#define QSCALE 0.18033688f  // 0.125 * log2(e) — folded into Q at projection time

typedef __attribute__((ext_vector_type(8))) __bf16 bf16x8;
typedef __attribute__((ext_vector_type(4))) __bf16 bf16x4;
typedef __attribute__((ext_vector_type(4))) float  f32x4;
typedef __attribute__((ext_vector_type(4))) short  short4v;

#define GPTR(p) ((__attribute__((address_space(1))) void*)(unsigned long long)(p))
#define LPTR(p) ((__attribute__((address_space(3))) void*)(p))

// ---------------- fused prep: cast x -> bf16, transpose 4 weights ----------------
__global__ __launch_bounds__(256) void k_prep(const float* __restrict__ x,
                                              __bf16* __restrict__ xb,
                                              const float* __restrict__ Wq,
                                              const float* __restrict__ Wk,
                                              const float* __restrict__ Wv,
                                              const float* __restrict__ Wo,
                                              __bf16* __restrict__ wqkt,
                                              __bf16* __restrict__ wvt,
                                              __bf16* __restrict__ wot) {
    const int bx = blockIdx.x;
    if (bx < 4096) {
        int i = bx * 2048 + threadIdx.x * 8;
        f32x4 a = *(const f32x4*)(x + i);
        f32x4 b = *(const f32x4*)(x + i + 4);
        bf16x8 o;
#pragma unroll
        for (int j = 0; j < 4; j++) { o[j] = (__bf16)a[j]; o[4 + j] = (__bf16)b[j]; }
        *(bf16x8*)(xb + i) = o;
        return;
    }
    __shared__ float t[32][33];
    const int tt = bx - 4096;
    const int widx = tt >> 10, r = tt & 1023;
    const float* W;
    __bf16* Wt;
    switch (widx) {
        case 0: W = Wq; Wt = wqkt; break;
        case 1: W = Wk; Wt = wqkt + (size_t)D_ * D_; break;
        case 2: W = Wv; Wt = wvt; break;
        default: W = Wo; Wt = wot; break;
    }
    const int i0 = (r & 31) * 32, j0 = (r >> 5) * 32;
    const int tx = threadIdx.x & 31, ty = threadIdx.x >> 5;
#pragma unroll
    for (int rr = 0; rr < 32; rr += 8)
        t[ty + rr][tx] = W[(size_t)(i0 + ty + rr) * D_ + j0 + tx];
    __syncthreads();
#pragma unroll
    for (int rr = 0; rr < 32; rr += 8)
        Wt[(size_t)(j0 + ty + rr) * D_ + i0 + tx] = (__bf16)t[tx][ty + rr];
}

// ---------------- 256x256 8-phase GEMM body (T3+T4: counted vmcnt) ----------------
// 8 waves (2M x 4N), per-wave 128x64 output, BK=64, LDS 128KiB dbuf.
// Per K-tile 4 phases = C-quadrants (qm,qn): (0,0),(1,0),(0,1),(1,1).
// Phase: 12 ds_read_b128 || stage 1 quarter of tile t+1 -> s_barrier ->
// lgkmcnt(0)+sched_barrier (rule #18) -> 16 MFMA (setprio) -> counted vmcnt ->
// s_barrier. Stage order A02,B0g,A13,B1g gives every unit >=2 phases in flight;
// vmcnt(4) at phase ends 1,2,4 (none at 3) -- NEVER 0 in steady state.
// B staged in qn-interleaved groups (group g holds Bt-rows {blk*64+g*32+j}) so
// stage units align with phase first-use. k-chunk XOR-swizzle by (row&7) over
// 8 chunks/row: each 8-lane group covers all 8 chunks -> conflict-free b128.
#define VMW(n) asm volatile("s_waitcnt vmcnt(" #n ")" ::: "memory")

#define PHASE(QM, QN, STAGE_STMT, WAIT_STMT) do {                                  \
    bf16x8 af[4][2], bfr[2][2];                                                    \
    _Pragma("unroll")                                                              \
    for (int mi = 0; mi < 4; mi++) {                                               \
        const int row = wr * 128 + (QM) * 64 + mi * 16 + l16;                      \
        _Pragma("unroll")                                                          \
        for (int ks = 0; ks < 2; ks++)                                             \
            af[mi][ks] = *(const bf16x8*)&Ac[row * 64 +                            \
                                             ((ks * 4 + quad) ^ (row & 7)) * 8];   \
    }                                                                              \
    _Pragma("unroll")                                                              \
    for (int ni = 0; ni < 2; ni++) {                                               \
        const int rho = wc * 32 + ni * 16 + l16;                                   \
        _Pragma("unroll")                                                          \
        for (int ks = 0; ks < 2; ks++)                                             \
            bfr[ni][ks] = *(const bf16x8*)&Bc[((QN) * 128 + rho) * 64 +            \
                                              ((ks * 4 + quad) ^ (rho & 7)) * 8];  \
    }                                                                              \
    STAGE_STMT;                                                                    \
    __builtin_amdgcn_s_barrier();                                                  \
    asm volatile("s_waitcnt lgkmcnt(0)" ::: "memory");                             \
    __builtin_amdgcn_sched_barrier(0);                                             \
    __builtin_amdgcn_s_setprio(1);                                                 \
    _Pragma("unroll")                                                              \
    for (int mi = 0; mi < 4; mi++)                                                 \
        _Pragma("unroll")                                                          \
        for (int ni = 0; ni < 2; ni++)                                             \
            _Pragma("unroll")                                                      \
            for (int ks = 0; ks < 2; ks++)                                         \
                acc[(QM) * 4 + mi][(QN) * 2 + ni] =                                \
                    __builtin_amdgcn_mfma_f32_16x16x32_bf16(                       \
                        af[mi][ks], bfr[ni][ks],                                   \
                        acc[(QM) * 4 + mi][(QN) * 2 + ni], 0, 0, 0);               \
    __builtin_amdgcn_s_setprio(0);                                                 \
    WAIT_STMT;                                                                     \
    __builtin_amdgcn_s_barrier();                                                  \
    __builtin_amdgcn_sched_barrier(0);                                             \
} while (0)

__device__ __forceinline__ void gemm256_body(const __bf16* __restrict__ Ag,
                                             const __bf16* __restrict__ Bg,
                                             __bf16* __restrict__ C,
                                             int N, int K, int tm, int tn,
                                             float scale, int vperm,
                                             __bf16* As0, __bf16* Bs0) {
    const int tid = threadIdx.x;
    const int wave = tid >> 6, lane = tid & 63;
    const int quad = lane >> 4, l16 = lane & 15;
    const int wr = wave >> 2, wc = wave & 3;
    f32x4 acc[8][4] = {};

    // A-unit u (64 rows [u*64,u*64+64)): 1 issue. pair p -> units {p, p+2}.
    auto stageA = [&](int kt, int pair) {
        __bf16* dst = As0 + (kt & 1) * 16384;
        const int k0 = kt * 64;
#pragma unroll
        for (int uu = 0; uu < 2; uu++) {
            const int u = pair + uu * 2;
            const int r = u * 64 + (tid >> 3);
            const int c = (tid & 7) ^ (r & 7);   // pre-swizzled source chunk
            __builtin_amdgcn_global_load_lds(
                GPTR(Ag + (size_t)(tm + r) * K + k0 + c * 8),
                LPTR(dst + u * 4096 + wave * 512), 16, 0, 0);
        }
    };
    // B group g: LDS rho in [0,128) holds Bt-row (rho>>5)*64 + g*32 + (rho&31).
    auto stageB = [&](int kt, int g) {
        __bf16* dst = Bs0 + (kt & 1) * 16384 + g * 8192;
        const int k0 = kt * 64;
#pragma unroll
        for (int s = 0; s < 2; s++) {
            const int rho = s * 64 + (tid >> 3);
            const int br  = (rho >> 5) * 64 + g * 32 + (rho & 31);
            const int c   = (tid & 7) ^ (rho & 7);
            __builtin_amdgcn_global_load_lds(
                GPTR(Bg + (size_t)(tn + br) * K + k0 + c * 8),
                LPTR(dst + s * 4096 + wave * 512), 16, 0, 0);
        }
    };

    // prologue: tile0 fully issued; first 4 (A02,B0g) landed, A13,B1g in flight
    stageA(0, 0); stageB(0, 0); stageA(0, 1); stageB(0, 1);
    VMW(4);
    __builtin_amdgcn_s_barrier();
    __builtin_amdgcn_sched_barrier(0);

    const int T = K >> 6;
    for (int kt = 0; kt < T; kt++) {
        const __bf16* Ac = As0 + (kt & 1) * 16384;
        const __bf16* Bc = Bs0 + (kt & 1) * 16384;
        const bool pre = (kt + 1 < T);
        // P1 (0,0): reads A02+B0g; stages (t+1).A02; end-wait completes t.A13
        PHASE(0, 0, { if (pre) stageA(kt + 1, 0); },
                    { if (pre) { VMW(4); } else { VMW(2); } });
        // P2 (1,0): reads A13; stages (t+1).B0g; end-wait completes t.B1g
        PHASE(1, 0, { if (pre) stageB(kt + 1, 0); },
                    { if (pre) { VMW(4); } else { VMW(0); } });
        // P3 (0,1): reads B1g; stages (t+1).A13; no wait needed
        PHASE(0, 1, { if (pre) stageA(kt + 1, 1); }, {});
        // P4 (1,1): nothing new read; stages (t+1).B1g; end-wait completes (t+1).A02,B0g
        PHASE(1, 1, { if (pre) stageB(kt + 1, 1); },
                    { if (pre) { VMW(4); } });
    }

#pragma unroll
    for (int mi = 0; mi < 8; mi++)
#pragma unroll
        for (int ni = 0; ni < 4; ni++)
#pragma unroll
            for (int r = 0; r < 4; r++) {
                const int row = tm + wr * 128 + (mi >> 2) * 64 + (mi & 3) * 16 +
                                quad * 4 + r;
                const int col = tn + wc * 64 + (ni >> 1) * 32 + (ni & 1) * 16 + l16;
                const int xr  = (vperm & (row >> 3) & 1) << 2;
                C[(size_t)row * N + (col ^ xr)] = (__bf16)(acc[mi][ni][r] * scale);
            }
}

// ---------------- fused QKV projection (256² 8-phase) ----------------
// qk part: tm-fastest (ids sharing an A-panel differ by 32 = 0 mod 8 -> same
// XCD). VT part: tn-fastest (xb-panel sharers same XCD; R9 verified 91->41MB).
__global__ __launch_bounds__(512, 2) void k_gemm_qkv(const __bf16* __restrict__ xb,
                                                     const __bf16* __restrict__ wqkt,
                                                     const __bf16* __restrict__ wvt,
                                                     __bf16* __restrict__ qk,
                                                     __bf16* __restrict__ VT) {
    __shared__ __bf16 As[2 * 16384];
    __shared__ __bf16 Bs[2 * 16384];
    const int bx = blockIdx.x;
    if (bx < 256) {
        const int tm = (bx & 31) * 256, tn = (bx >> 5) * 256;
        const float scale = (tn < D_) ? QSCALE : 1.0f;
        gemm256_body(xb, wqkt, qk, QKS, D_, tm, tn, scale, 0, As, Bs);
    } else {
        const int b2 = bx - 256;
        const int tn = (b2 & 31) * 256, tm = (b2 >> 5) * 256;
        gemm256_body(wvt, xb, VT, NTOK, D_, tm, tn, 1.0f, 1, As, Bs);
    }
}

// ---------------- output GEMM: out = ctx Wo + bo (R9 128² body) ----------------
// 256² would give only 128 blocks (< 256 CUs) for N=1024 -> keep 128² grid 512.
__global__ __launch_bounds__(256) void k_gemm_o(const __bf16* __restrict__ A,
                                                const __bf16* __restrict__ Bt,
                                                float* __restrict__ C,
                                                const float* __restrict__ bias) {
    __shared__ __bf16 As[128 * 32];
    __shared__ __bf16 Bs[128 * 32];
    const int tid  = threadIdx.x;
    const int wave = tid >> 6, lane = tid & 63;
    const int quad = lane >> 4, l16 = lane & 15;
    const int tm = blockIdx.x * 128, tn = blockIdx.y * 128;
    const int wm = (wave & 1) * 64, wn = (wave >> 1) * 64;
    const int N = D_, K = D_;
    f32x4 acc[4][4] = {};

    for (int k0 = 0; k0 < K; k0 += 32) {
        __syncthreads();
#pragma unroll
        for (int s = 0; s < 2; s++) {
            const int cb = s * 256 + wave * 64;
            const int c  = cb + lane;
            const int row = c >> 2;
            const int kc  = ((c & 3) ^ ((row >> 1) & 3)) * 8;  // swizzled k-chunk
            __builtin_amdgcn_global_load_lds(GPTR(A + (size_t)(tm + row) * K + k0 + kc),
                                             LPTR(As + cb * 8), 16, 0, 0);
            __builtin_amdgcn_global_load_lds(GPTR(Bt + (size_t)(tn + row) * K + k0 + kc),
                                             LPTR(Bs + cb * 8), 16, 0, 0);
        }
        __syncthreads();

        bf16x8 af[4], bf[4];
#pragma unroll
        for (int mi = 0; mi < 4; mi++) {
            const int rf = wm + mi * 16 + l16;
            af[mi] = *(const bf16x8*)&As[rf * 32 + (quad ^ ((rf >> 1) & 3)) * 8];
        }
#pragma unroll
        for (int ni = 0; ni < 4; ni++) {
            const int rf = wn + ni * 16 + l16;
            bf[ni] = *(const bf16x8*)&Bs[rf * 32 + (quad ^ ((rf >> 1) & 3)) * 8];
        }
#pragma unroll
        for (int mi = 0; mi < 4; mi++)
#pragma unroll
            for (int ni = 0; ni < 4; ni++)
                acc[mi][ni] = __builtin_amdgcn_mfma_f32_16x16x32_bf16(
                    af[mi], bf[ni], acc[mi][ni], 0, 0, 0);
    }

#pragma unroll
    for (int mi = 0; mi < 4; mi++)
#pragma unroll
        for (int ni = 0; ni < 4; ni++)
#pragma unroll
            for (int r = 0; r < 4; r++) {
                const int row = tm + wm + mi * 16 + quad * 4 + r;
                const int col = tn + wn + ni * 16 + l16;
                C[(size_t)row * N + col] = acc[mi][ni][r] + bias[col];
            }
}

__device__ __forceinline__ short bf16_bits(float f) {
    __bf16 h = (__bf16)f;
    return __builtin_bit_cast(short, h);
}

// ---------------- causal flash attention ----------------
// R9 structure: XCD-aware block grouping. bid = g*64 + qp*8 + r, (h,b) = g*8+r.
// All 8 qp-blocks sharing one (h,b)'s K/V stream land on one XCD's L2.
// Two-pass qt pairing (qp, 15-qp) -> uniform 34 k-iters/block. Conflict-free
// V path: vperm'd VT producer + (l16>>3) XOR on half-select (R7: 4.3M -> 0).
__global__ __launch_bounds__(256, 2) void k_attn(const __bf16* __restrict__ Qb,
                                                 const __bf16* __restrict__ Kb,
                                                 const __bf16* __restrict__ VT,
                                                 __bf16* __restrict__ ctx) {
    __shared__ __bf16 Ks[2][64 * 64];   // [kv][hd], 16B-chunk XOR-swizzled
    __shared__ __bf16 Vs[2][64 * 64];   // [hd][kv], 16B-chunk XOR-swizzled (+vperm)

    const int tid = threadIdx.x;
    const int wave = tid >> 6, lane = tid & 63;
    const int quad = lane >> 4, l16 = lane & 15;
    const int bid = blockIdx.x;
    const int hb  = ((bid >> 6) << 3) | (bid & 7);   // (h,b) group, fixed per XCD residue
    const int qp  = (bid >> 3) & 7;                  // q-pair index within the group
    const int h = hb >> 2, b = hb & 3;
    const size_t tok0 = (size_t)b * S_;
    const size_t hoff = (size_t)h * HD_;

    auto stage = [&](int kv, int buf) {
#pragma unroll
        for (int s = 0; s < 2; s++) {
            const int cb = s * 256 + wave * 64;
            const int c  = cb + lane;
            const int row = c >> 3;
            const int gc  = (c & 7) ^ (row & 7);
            __builtin_amdgcn_global_load_lds(
                GPTR(Kb + (size_t)(tok0 + kv + row) * QKS + hoff + gc * 8),
                LPTR(&Ks[buf][cb * 8]), 16, 0, 0);
            __builtin_amdgcn_global_load_lds(
                GPTR(VT + (hoff + row) * (size_t)NTOK + tok0 + kv + gc * 8),
                LPTR(&Vs[buf][cb * 8]), 16, 0, 0);
        }
    };

#pragma unroll 1
    for (int sidx = 0; sidx < 2; sidx++) {
        const int qt = sidx == 0 ? qp : 15 - qp;
        const int qb = qt * 128;
        const int q0 = qb + wave * 32;

        // Q as B-operand: B[k=hd=quad*8+j][n=q=l16]
        bf16x8 qf[2][2];
#pragma unroll
        for (int qi = 0; qi < 2; qi++)
#pragma unroll
            for (int ks = 0; ks < 2; ks++)
                qf[qi][ks] = *(const bf16x8*)&Qb[(tok0 + q0 + qi * 16 + l16) * QKS +
                                                 hoff + ks * 32 + quad * 8];

        f32x4 oacc[2][4] = {};     // O^T[hd = hs*16+quad*4+r][q = qi*16+l16]
        float lsum[2] = {0.f, 0.f};
        const int ktb = (qb + 127) >> 6;

        stage(0, 0);
        __syncthreads();

        for (int kt = 0; kt <= ktb; kt++) {
            const int cur = kt & 1;
            const int kv0 = kt * 64;
            if (kt < ktb) stage(kv0 + 64, 1 - cur);   // prefetch overlaps compute

            if (kv0 <= q0 + 31) {
                // S^T = K(A) · Q(B)
                f32x4 st[2][4] = {};
#pragma unroll
                for (int ks = 0; ks < 2; ks++)
#pragma unroll
                    for (int ksub = 0; ksub < 4; ksub++) {
                        const int r = ksub * 16 + l16;
                        bf16x8 kf = *(const bf16x8*)
                            &Ks[cur][(r * 8 + (((ks * 4 + quad) ^ (r & 7)))) * 8];
#pragma unroll
                        for (int qi = 0; qi < 2; qi++)
                            st[qi][ksub] = __builtin_amdgcn_mfma_f32_16x16x32_bf16(
                                kf, qf[qi][ks], st[qi][ksub], 0, 0, 0);
                    }
                if (kv0 + 63 > q0) {   // diagonal tiles: causal mask on S^T
#pragma unroll
                    for (int qi = 0; qi < 2; qi++)
#pragma unroll
                        for (int ksub = 0; ksub < 4; ksub++)
#pragma unroll
                            for (int r = 0; r < 4; r++) {
                                const int kg = kv0 + ksub * 16 + quad * 4 + r;
                                const int qg = q0 + qi * 16 + l16;
                                if (kg > qg) st[qi][ksub][r] = -1e30f;
                            }
                }
                // p = exp2(s); pack P^T into B-frags (registers)
                short4v pfrag[2][4];
#pragma unroll
                for (int qi = 0; qi < 2; qi++)
#pragma unroll
                    for (int ksub = 0; ksub < 4; ksub++) {
                        float p0 = __builtin_amdgcn_exp2f(st[qi][ksub][0]);
                        float p1 = __builtin_amdgcn_exp2f(st[qi][ksub][1]);
                        float p2 = __builtin_amdgcn_exp2f(st[qi][ksub][2]);
                        float p3 = __builtin_amdgcn_exp2f(st[qi][ksub][3]);
                        lsum[qi] += (p0 + p1) + (p2 + p3);
                        short4v pf = {bf16_bits(p0), bf16_bits(p1),
                                      bf16_bits(p2), bf16_bits(p3)};
                        pfrag[qi][ksub] = pf;
                    }
                // O^T += V^T(A) · P^T(B), K=16 MFMAs
#pragma unroll
                for (int ksub = 0; ksub < 4; ksub++)
#pragma unroll
                    for (int hs = 0; hs < 4; hs++) {
                        const int row = hs * 16 + l16;
                        const int swz = (ksub * 2 + (quad >> 1)) ^ (row & 7);
                        short4v vf = *(const short4v*)
                            &Vs[cur][row * 64 + swz * 8 + ((quad ^ (l16 >> 3)) & 1) * 4];
#pragma unroll
                        for (int qi = 0; qi < 2; qi++)
                            oacc[qi][hs] = __builtin_amdgcn_mfma_f32_16x16x16bf16_1k(
                                vf, pfrag[qi][ksub], oacc[qi][hs], 0, 0, 0);
                    }
            }
            __syncthreads();
        }

        // l reduce + epilogue (8B stores, r contiguous in hd)
#pragma unroll
        for (int qi = 0; qi < 2; qi++) {
            float v = lsum[qi];
            v += __shfl_xor(v, 16);
            v += __shfl_xor(v, 32);
            const float rl = 1.0f / v;
#pragma unroll
            for (int hs = 0; hs < 4; hs++) {
                bf16x4 o;
#pragma unroll
                for (int r = 0; r < 4; r++) o[r] = (__bf16)(oacc[qi][hs][r] * rl);
                *(bf16x4*)&ctx[(tok0 + q0 + qi * 16 + l16) * D_ + hoff +
                               hs * 16 + quad * 4] = o;
            }
        }
    }
}

// ---------------- launch ----------------
extern "C" void kernel_launch(void* const* d_in, const int* in_sizes, int n_in,
                              void* d_out, int out_size, void* d_ws, size_t ws_size,
                              hipStream_t stream) {
    const float* x  = (const float*)d_in[0];
    const float* Wq = (const float*)d_in[1];
    const float* Wk = (const float*)d_in[2];
    const float* Wv = (const float*)d_in[3];
    const float* Wo = (const float*)d_in[4];
    const float* bo = (const float*)d_in[5];
    float* out = (float*)d_out;

    char* p = (char*)d_ws;
    __bf16* xb   = (__bf16*)p; p += (size_t)NTOK * D_ * 2;   // 16 MB
    __bf16* wqkt = (__bf16*)p; p += (size_t)2 * D_ * D_ * 2; // 4 MB
    __bf16* wvt  = (__bf16*)p; p += (size_t)D_ * D_ * 2;     // 2 MB
    __bf16* wot  = (__bf16*)p; p += (size_t)D_ * D_ * 2;     // 2 MB
    __bf16* qk   = (__bf16*)p; p += (size_t)NTOK * QKS * 2;  // 32 MB [tok][Q|K]
    __bf16* VT   = (__bf16*)p; p += (size_t)NTOK * D_ * 2;   // 16 MB [d][tok]
    __bf16* ctx  = (__bf16*)p; p += (size_t)NTOK * D_ * 2;   // 16 MB

    k_prep<<<dim3(4096 + 4 * 1024), 256, 0, stream>>>(x, xb, Wq, Wk, Wv, Wo,
                                                      wqkt, wvt, wot);
    k_gemm_qkv<<<dim3(256 + 128), 512, 0, stream>>>(xb, wqkt, wvt, qk, VT);
    k_attn<<<dim3(512), 256, 0, stream>>>(qk, qk + D_, VT, ctx);
    k_gemm_o<<<dim3(64, 8), 256, 0, stream>>>(ctx, wot, out, bo);
}

// Round 6
// 254.346 us; speedup vs baseline: 1.0148x; 1.0148x over previous
//
#include <hip/hip_runtime.h>

#define S_   2048
#define D_   1024
#define H_   16
#define HD_  64
#define NTOK 8192   // B*S
#define QKS  2048   // row stride of fused QK output
#define QSCALE 0.18033688f  // 0.125 * log2(e) — folded into Q at projection time

typedef __attribute__((ext_vector_type(8))) __bf16 bf16x8;
typedef __attribute__((ext_vector_type(4))) __bf16 bf16x4;
typedef __attribute__((ext_vector_type(4))) float  f32x4;
typedef __attribute__((ext_vector_type(4))) short  short4v;

#define GPTR(p) ((__attribute__((address_space(1))) void*)(unsigned long long)(p))
#define LPTR(p) ((__attribute__((address_space(3))) void*)(p))

// ---------------- fused prep: cast x -> bf16, transpose 4 weights ----------------
__global__ __launch_bounds__(256) void k_prep(const float* __restrict__ x,
                                              __bf16* __restrict__ xb,
                                              const float* __restrict__ Wq,
                                              const float* __restrict__ Wk,
                                              const float* __restrict__ Wv,
                                              const float* __restrict__ Wo,
                                              __bf16* __restrict__ wqkt,
                                              __bf16* __restrict__ wvt,
                                              __bf16* __restrict__ wot) {
    const int bx = blockIdx.x;
    if (bx < 4096) {
        int i = bx * 2048 + threadIdx.x * 8;
        f32x4 a = *(const f32x4*)(x + i);
        f32x4 b = *(const f32x4*)(x + i + 4);
        bf16x8 o;
#pragma unroll
        for (int j = 0; j < 4; j++) { o[j] = (__bf16)a[j]; o[4 + j] = (__bf16)b[j]; }
        *(bf16x8*)(xb + i) = o;
        return;
    }
    __shared__ float t[32][33];
    const int tt = bx - 4096;
    const int widx = tt >> 10, r = tt & 1023;
    const float* W;
    __bf16* Wt;
    switch (widx) {
        case 0: W = Wq; Wt = wqkt; break;
        case 1: W = Wk; Wt = wqkt + (size_t)D_ * D_; break;
        case 2: W = Wv; Wt = wvt; break;
        default: W = Wo; Wt = wot; break;
    }
    const int i0 = (r & 31) * 32, j0 = (r >> 5) * 32;
    const int tx = threadIdx.x & 31, ty = threadIdx.x >> 5;
#pragma unroll
    for (int rr = 0; rr < 32; rr += 8)
        t[ty + rr][tx] = W[(size_t)(i0 + ty + rr) * D_ + j0 + tx];
    __syncthreads();
#pragma unroll
    for (int rr = 0; rr < 32; rr += 8)
        Wt[(size_t)(j0 + ty + rr) * D_ + i0 + tx] = (__bf16)t[tx][ty + rr];
}

// ---------------- 256x128 BK=64 8-wave GEMM body ----------------
// R12: fixes R11's two failure causes. (1) Grid quantization: 256x128 tiles
// give 768 qkv blocks = exactly 3 generations at 1 block/CU (96KB LDS).
// (2) LDS traffic: 16 ds_read_b128 per K-tile per wave for 32 MFMAs (1:2),
// fragments read once. One barrier per K-tile; all 6 stage-issues at tile top
// so the barrier's implicit vmcnt(0) drains loads issued a full tile (~300cy)
// earlier -- covers the L2-hit latency that dominates (panels XCD-resident).
// Layout: rows x 64k, 8 chunks of 8 bf16/row, chunk XOR (row&7): linear LDS
// dest + pre-swizzled global source (rule #21); fragment reads at chunk
// (ks*4+quad)^(row&7) -- same pattern as attn's Ks reads, measured 0 conflicts.
// vperm=1: swap 8B halves of 16B output chunks for rows with bit3 set
// (consumed by k_attn's V-read; verified R7: attn bank conflicts 4.3M -> 0).
__device__ __forceinline__ void gemm_body_256x128(const __bf16* __restrict__ A,
                                                  const __bf16* __restrict__ Bt,
                                                  __bf16* __restrict__ C,
                                                  int N, int K, int tm, int tn,
                                                  float scale, int vperm,
                                                  __bf16* As, __bf16* Bs) {
    const int tid  = threadIdx.x;
    const int wave = tid >> 6, lane = tid & 63;
    const int quad = lane >> 4, l16 = lane & 15;
    const int wrow = (wave >> 1) * 64, wcol = (wave & 1) * 64;
    const int lr = lane >> 3, lc = lane & 7;
    f32x4 acc[4][4] = {};

    // A tile 256x64 = 4 insts, B tile 128x64 = 2 insts (512 lanes x 16B each).
    // LDS dest linear (row*64 + lc*8); source chunk pre-swizzled: cs = lc ^ (r&7).
    auto stage = [&](int kt) {
        const int k0 = kt * 64;
        __bf16* Ad = As + (kt & 1) * 16384;
        __bf16* Bd = Bs + (kt & 1) * 8192;
        const int cs = (lc ^ lr) * 8;   // r&7 == lr for all staged rows
#pragma unroll
        for (int u = 0; u < 4; u++) {
            const int r = u * 64 + wave * 8 + lr;
            __builtin_amdgcn_global_load_lds(GPTR(A + (size_t)(tm + r) * K + k0 + cs),
                                             LPTR(Ad + (u * 64 + wave * 8) * 64), 16, 0, 0);
        }
#pragma unroll
        for (int u = 0; u < 2; u++) {
            const int r = u * 64 + wave * 8 + lr;
            __builtin_amdgcn_global_load_lds(GPTR(Bt + (size_t)(tn + r) * K + k0 + cs),
                                             LPTR(Bd + (u * 64 + wave * 8) * 64), 16, 0, 0);
        }
    };

    stage(0);
    __syncthreads();   // implicit vmcnt(0): tile0 landed

    const int T = K >> 6;
    for (int kt = 0; kt < T; kt++) {
        if (kt + 1 < T) stage(kt + 1);   // issue next tile first: full-tile cover

        const __bf16* Ac = As + (kt & 1) * 16384;
        const __bf16* Bc = Bs + (kt & 1) * 8192;
        bf16x8 af[4][2], bf[4][2];
#pragma unroll
        for (int mi = 0; mi < 4; mi++) {
            const int row = wrow + mi * 16 + l16;
#pragma unroll
            for (int ks = 0; ks < 2; ks++)
                af[mi][ks] = *(const bf16x8*)&Ac[row * 64 + ((ks * 4 + quad) ^ (row & 7)) * 8];
        }
#pragma unroll
        for (int ni = 0; ni < 4; ni++) {
            const int row = wcol + ni * 16 + l16;
#pragma unroll
            for (int ks = 0; ks < 2; ks++)
                bf[ni][ks] = *(const bf16x8*)&Bc[row * 64 + ((ks * 4 + quad) ^ (row & 7)) * 8];
        }
#pragma unroll
        for (int ks = 0; ks < 2; ks++)
#pragma unroll
            for (int mi = 0; mi < 4; mi++)
#pragma unroll
                for (int ni = 0; ni < 4; ni++)
                    acc[mi][ni] = __builtin_amdgcn_mfma_f32_16x16x32_bf16(
                        af[mi][ks], bf[ni][ks], acc[mi][ni], 0, 0, 0);

        __syncthreads();   // all reads of cur done; next buf landed (vmcnt(0))
    }

#pragma unroll
    for (int mi = 0; mi < 4; mi++)
#pragma unroll
        for (int ni = 0; ni < 4; ni++)
#pragma unroll
            for (int r = 0; r < 4; r++) {
                const int row = tm + wrow + mi * 16 + quad * 4 + r;
                const int col = tn + wcol + ni * 16 + l16;
                const int xr  = (vperm & (row >> 3) & 1) << 2;
                C[(size_t)row * N + (col ^ xr)] = (__bf16)(acc[mi][ni][r] * scale);
            }
}

// ---------------- fused QKV projection ----------------
// qk part: 512 blocks, tm-fastest (ids sharing an xb A-panel differ by 32 ==
// 0 mod 8 -> same XCD). VT part: 256 blocks, tn-fastest (xb-panel sharers
// differ by 64 -> same XCD; R9 verified FETCH 91->41MB). 768 = 3 x 256 CUs.
__global__ __launch_bounds__(512, 2) void k_gemm_qkv(const __bf16* __restrict__ xb,
                                                     const __bf16* __restrict__ wqkt,
                                                     const __bf16* __restrict__ wvt,
                                                     __bf16* __restrict__ qk,
                                                     __bf16* __restrict__ VT) {
    __shared__ __bf16 As[2 * 16384];   // 64 KB
    __shared__ __bf16 Bs[2 * 8192];    // 32 KB
    const int bx = blockIdx.x;
    if (bx < 512) {
        const int tm = (bx & 31) * 256, tn = (bx >> 5) * 128;
        const float scale = (tn < D_) ? QSCALE : 1.0f;
        gemm_body_256x128(xb, wqkt, qk, QKS, D_, tm, tn, scale, 0, As, Bs);
    } else {
        const int b2 = bx - 512;
        const int tn = (b2 & 63) * 128, tm = (b2 >> 6) * 256;
        gemm_body_256x128(wvt, xb, VT, NTOK, D_, tm, tn, 1.0f, 1, As, Bs);
    }
}

// ---------------- output GEMM: out = ctx Wo + bo (fp32 epilogue) ----------------
// Same 256x128 body; 32x8 = 256 blocks = exactly 1 generation.
__global__ __launch_bounds__(512, 2) void k_gemm_o(const __bf16* __restrict__ A,
                                                   const __bf16* __restrict__ Bt,
                                                   float* __restrict__ C,
                                                   const float* __restrict__ bias) {
    __shared__ __bf16 As[2 * 16384];
    __shared__ __bf16 Bs[2 * 8192];
    const int tid  = threadIdx.x;
    const int wave = tid >> 6, lane = tid & 63;
    const int quad = lane >> 4, l16 = lane & 15;
    const int wrow = (wave >> 1) * 64, wcol = (wave & 1) * 64;
    const int lr = lane >> 3, lc = lane & 7;
    const int tm = (blockIdx.x & 31) * 256, tn = (blockIdx.x >> 5) * 128;
    const int N = D_, K = D_;
    f32x4 acc[4][4] = {};

    auto stage = [&](int kt) {
        const int k0 = kt * 64;
        __bf16* Ad = As + (kt & 1) * 16384;
        __bf16* Bd = Bs + (kt & 1) * 8192;
        const int cs = (lc ^ lr) * 8;
#pragma unroll
        for (int u = 0; u < 4; u++) {
            const int r = u * 64 + wave * 8 + lr;
            __builtin_amdgcn_global_load_lds(GPTR(A + (size_t)(tm + r) * K + k0 + cs),
                                             LPTR(Ad + (u * 64 + wave * 8) * 64), 16, 0, 0);
        }
#pragma unroll
        for (int u = 0; u < 2; u++) {
            const int r = u * 64 + wave * 8 + lr;
            __builtin_amdgcn_global_load_lds(GPTR(Bt + (size_t)(tn + r) * K + k0 + cs),
                                             LPTR(Bd + (u * 64 + wave * 8) * 64), 16, 0, 0);
        }
    };

    stage(0);
    __syncthreads();

    const int T = K >> 6;
    for (int kt = 0; kt < T; kt++) {
        if (kt + 1 < T) stage(kt + 1);

        const __bf16* Ac = As + (kt & 1) * 16384;
        const __bf16* Bc = Bs + (kt & 1) * 8192;
        bf16x8 af[4][2], bf[4][2];
#pragma unroll
        for (int mi = 0; mi < 4; mi++) {
            const int row = wrow + mi * 16 + l16;
#pragma unroll
            for (int ks = 0; ks < 2; ks++)
                af[mi][ks] = *(const bf16x8*)&Ac[row * 64 + ((ks * 4 + quad) ^ (row & 7)) * 8];
        }
#pragma unroll
        for (int ni = 0; ni < 4; ni++) {
            const int row = wcol + ni * 16 + l16;
#pragma unroll
            for (int ks = 0; ks < 2; ks++)
                bf[ni][ks] = *(const bf16x8*)&Bc[row * 64 + ((ks * 4 + quad) ^ (row & 7)) * 8];
        }
#pragma unroll
        for (int ks = 0; ks < 2; ks++)
#pragma unroll
            for (int mi = 0; mi < 4; mi++)
#pragma unroll
                for (int ni = 0; ni < 4; ni++)
                    acc[mi][ni] = __builtin_amdgcn_mfma_f32_16x16x32_bf16(
                        af[mi][ks], bf[ni][ks], acc[mi][ni], 0, 0, 0);

        __syncthreads();
    }

#pragma unroll
    for (int mi = 0; mi < 4; mi++)
#pragma unroll
        for (int ni = 0; ni < 4; ni++)
#pragma unroll
            for (int r = 0; r < 4; r++) {
                const int row = tm + wrow + mi * 16 + quad * 4 + r;
                const int col = tn + wcol + ni * 16 + l16;
                C[(size_t)row * N + col] = acc[mi][ni][r] + bias[col];
            }
}

__device__ __forceinline__ short bf16_bits(float f) {
    __bf16 h = (__bf16)f;
    return __builtin_bit_cast(short, h);
}

// ---------------- causal flash attention ----------------
// R9 structure (unchanged): XCD-aware grouping. bid = g*64 + qp*8 + r,
// (h,b) = g*8+r -> all 8 qp-blocks sharing one (h,b)'s K/V stream on one XCD.
// Two-pass qt pairing (qp, 15-qp) -> uniform 34 k-iters/block. Conflict-free
// V path: vperm'd VT producer + (l16>>3) XOR on half-select (R7: 4.3M -> 0).
__global__ __launch_bounds__(256, 2) void k_attn(const __bf16* __restrict__ Qb,
                                                 const __bf16* __restrict__ Kb,
                                                 const __bf16* __restrict__ VT,
                                                 __bf16* __restrict__ ctx) {
    __shared__ __bf16 Ks[2][64 * 64];   // [kv][hd], 16B-chunk XOR-swizzled
    __shared__ __bf16 Vs[2][64 * 64];   // [hd][kv], 16B-chunk XOR-swizzled (+vperm)

    const int tid = threadIdx.x;
    const int wave = tid >> 6, lane = tid & 63;
    const int quad = lane >> 4, l16 = lane & 15;
    const int bid = blockIdx.x;
    const int hb  = ((bid >> 6) << 3) | (bid & 7);   // (h,b) group, fixed per XCD residue
    const int qp  = (bid >> 3) & 7;                  // q-pair index within the group
    const int h = hb >> 2, b = hb & 3;
    const size_t tok0 = (size_t)b * S_;
    const size_t hoff = (size_t)h * HD_;

    auto stage = [&](int kv, int buf) {
#pragma unroll
        for (int s = 0; s < 2; s++) {
            const int cb = s * 256 + wave * 64;
            const int c  = cb + lane;
            const int row = c >> 3;
            const int gc  = (c & 7) ^ (row & 7);
            __builtin_amdgcn_global_load_lds(
                GPTR(Kb + (size_t)(tok0 + kv + row) * QKS + hoff + gc * 8),
                LPTR(&Ks[buf][cb * 8]), 16, 0, 0);
            __builtin_amdgcn_global_load_lds(
                GPTR(VT + (hoff + row) * (size_t)NTOK + tok0 + kv + gc * 8),
                LPTR(&Vs[buf][cb * 8]), 16, 0, 0);
        }
    };

#pragma unroll 1
    for (int sidx = 0; sidx < 2; sidx++) {
        const int qt = sidx == 0 ? qp : 15 - qp;
        const int qb = qt * 128;
        const int q0 = qb + wave * 32;

        // Q as B-operand: B[k=hd=quad*8+j][n=q=l16]
        bf16x8 qf[2][2];
#pragma unroll
        for (int qi = 0; qi < 2; qi++)
#pragma unroll
            for (int ks = 0; ks < 2; ks++)
                qf[qi][ks] = *(const bf16x8*)&Qb[(tok0 + q0 + qi * 16 + l16) * QKS +
                                                 hoff + ks * 32 + quad * 8];

        f32x4 oacc[2][4] = {};     // O^T[hd = hs*16+quad*4+r][q = qi*16+l16]
        float lsum[2] = {0.f, 0.f};
        const int ktb = (qb + 127) >> 6;

        stage(0, 0);
        __syncthreads();

        for (int kt = 0; kt <= ktb; kt++) {
            const int cur = kt & 1;
            const int kv0 = kt * 64;
            if (kt < ktb) stage(kv0 + 64, 1 - cur);   // prefetch overlaps compute

            if (kv0 <= q0 + 31) {
                // S^T = K(A) · Q(B)
                f32x4 st[2][4] = {};
#pragma unroll
                for (int ks = 0; ks < 2; ks++)
#pragma unroll
                    for (int ksub = 0; ksub < 4; ksub++) {
                        const int r = ksub * 16 + l16;
                        bf16x8 kf = *(const bf16x8*)
                            &Ks[cur][(r * 8 + (((ks * 4 + quad) ^ (r & 7)))) * 8];
#pragma unroll
                        for (int qi = 0; qi < 2; qi++)
                            st[qi][ksub] = __builtin_amdgcn_mfma_f32_16x16x32_bf16(
                                kf, qf[qi][ks], st[qi][ksub], 0, 0, 0);
                    }
                if (kv0 + 63 > q0) {   // diagonal tiles: causal mask on S^T
#pragma unroll
                    for (int qi = 0; qi < 2; qi++)
#pragma unroll
                        for (int ksub = 0; ksub < 4; ksub++)
#pragma unroll
                            for (int r = 0; r < 4; r++) {
                                const int kg = kv0 + ksub * 16 + quad * 4 + r;
                                const int qg = q0 + qi * 16 + l16;
                                if (kg > qg) st[qi][ksub][r] = -1e30f;
                            }
                }
                // p = exp2(s); pack P^T into B-frags (registers)
                short4v pfrag[2][4];
#pragma unroll
                for (int qi = 0; qi < 2; qi++)
#pragma unroll
                    for (int ksub = 0; ksub < 4; ksub++) {
                        float p0 = __builtin_amdgcn_exp2f(st[qi][ksub][0]);
                        float p1 = __builtin_amdgcn_exp2f(st[qi][ksub][1]);
                        float p2 = __builtin_amdgcn_exp2f(st[qi][ksub][2]);
                        float p3 = __builtin_amdgcn_exp2f(st[qi][ksub][3]);
                        lsum[qi] += (p0 + p1) + (p2 + p3);
                        short4v pf = {bf16_bits(p0), bf16_bits(p1),
                                      bf16_bits(p2), bf16_bits(p3)};
                        pfrag[qi][ksub] = pf;
                    }
                // O^T += V^T(A) · P^T(B), K=16 MFMAs
#pragma unroll
                for (int ksub = 0; ksub < 4; ksub++)
#pragma unroll
                    for (int hs = 0; hs < 4; hs++) {
                        const int row = hs * 16 + l16;
                        const int swz = (ksub * 2 + (quad >> 1)) ^ (row & 7);
                        short4v vf = *(const short4v*)
                            &Vs[cur][row * 64 + swz * 8 + ((quad ^ (l16 >> 3)) & 1) * 4];
#pragma unroll
                        for (int qi = 0; qi < 2; qi++)
                            oacc[qi][hs] = __builtin_amdgcn_mfma_f32_16x16x16bf16_1k(
                                vf, pfrag[qi][ksub], oacc[qi][hs], 0, 0, 0);
                    }
            }
            __syncthreads();
        }

        // l reduce + epilogue (8B stores, r contiguous in hd)
#pragma unroll
        for (int qi = 0; qi < 2; qi++) {
            float v = lsum[qi];
            v += __shfl_xor(v, 16);
            v += __shfl_xor(v, 32);
            const float rl = 1.0f / v;
#pragma unroll
            for (int hs = 0; hs < 4; hs++) {
                bf16x4 o;
#pragma unroll
                for (int r = 0; r < 4; r++) o[r] = (__bf16)(oacc[qi][hs][r] * rl);
                *(bf16x4*)&ctx[(tok0 + q0 + qi * 16 + l16) * D_ + hoff +
                               hs * 16 + quad * 4] = o;
            }
        }
    }
}

// ---------------- launch ----------------
extern "C" void kernel_launch(void* const* d_in, const int* in_sizes, int n_in,
                              void* d_out, int out_size, void* d_ws, size_t ws_size,
                              hipStream_t stream) {
    const float* x  = (const float*)d_in[0];
    const float* Wq = (const float*)d_in[1];
    const float* Wk = (const float*)d_in[2];
    const float* Wv = (const float*)d_in[3];
    const float* Wo = (const float*)d_in[4];
    const float* bo = (const float*)d_in[5];
    float* out = (float*)d_out;

    char* p = (char*)d_ws;
    __bf16* xb   = (__bf16*)p; p += (size_t)NTOK * D_ * 2;   // 16 MB
    __bf16* wqkt = (__bf16*)p; p += (size_t)2 * D_ * D_ * 2; // 4 MB
    __bf16* wvt  = (__bf16*)p; p += (size_t)D_ * D_ * 2;     // 2 MB
    __bf16* wot  = (__bf16*)p; p += (size_t)D_ * D_ * 2;     // 2 MB
    __bf16* qk   = (__bf16*)p; p += (size_t)NTOK * QKS * 2;  // 32 MB [tok][Q|K]
    __bf16* VT   = (__bf16*)p; p += (size_t)NTOK * D_ * 2;   // 16 MB [d][tok]
    __bf16* ctx  = (__bf16*)p; p += (size_t)NTOK * D_ * 2;   // 16 MB

    k_prep<<<dim3(4096 + 4 * 1024), 256, 0, stream>>>(x, xb, Wq, Wk, Wv, Wo,
                                                      wqkt, wvt, wot);
    k_gemm_qkv<<<dim3(512 + 256), 512, 0, stream>>>(xb, wqkt, wvt, qk, VT);
    k_attn<<<dim3(512), 256, 0, stream>>>(qk, qk + D_, VT, ctx);
    k_gemm_o<<<dim3(256), 512, 0, stream>>>(ctx, wot, out, bo);
}

// Round 7
// 238.148 us; speedup vs baseline: 1.0838x; 1.0680x over previous
//
#include <hip/hip_runtime.h>

#define S_   2048
#define D_   1024
#define H_   16
#define HD_  64
#define NTOK 8192   // B*S
#define QKS  2048   // row stride of fused QK output
#define QSCALE 0.18033688f  // 0.125 * log2(e) — folded into Q at projection time

typedef __attribute__((ext_vector_type(8))) __bf16 bf16x8;
typedef __attribute__((ext_vector_type(4))) __bf16 bf16x4;
typedef __attribute__((ext_vector_type(4))) float  f32x4;
typedef __attribute__((ext_vector_type(4))) short  short4v;

#define GPTR(p) ((__attribute__((address_space(1))) void*)(unsigned long long)(p))
#define LPTR(p) ((__attribute__((address_space(3))) void*)(p))

// ---------------- fused prep: cast x -> bf16, transpose 4 weights ----------------
__global__ __launch_bounds__(256) void k_prep(const float* __restrict__ x,
                                              __bf16* __restrict__ xb,
                                              const float* __restrict__ Wq,
                                              const float* __restrict__ Wk,
                                              const float* __restrict__ Wv,
                                              const float* __restrict__ Wo,
                                              __bf16* __restrict__ wqkt,
                                              __bf16* __restrict__ wvt,
                                              __bf16* __restrict__ wot) {
    const int bx = blockIdx.x;
    if (bx < 4096) {
        int i = bx * 2048 + threadIdx.x * 8;
        f32x4 a = *(const f32x4*)(x + i);
        f32x4 b = *(const f32x4*)(x + i + 4);
        bf16x8 o;
#pragma unroll
        for (int j = 0; j < 4; j++) { o[j] = (__bf16)a[j]; o[4 + j] = (__bf16)b[j]; }
        *(bf16x8*)(xb + i) = o;
        return;
    }
    __shared__ float t[32][33];
    const int tt = bx - 4096;
    const int widx = tt >> 10, r = tt & 1023;
    const float* W;
    __bf16* Wt;
    switch (widx) {
        case 0: W = Wq; Wt = wqkt; break;
        case 1: W = Wk; Wt = wqkt + (size_t)D_ * D_; break;
        case 2: W = Wv; Wt = wvt; break;
        default: W = Wo; Wt = wot; break;
    }
    const int i0 = (r & 31) * 32, j0 = (r >> 5) * 32;
    const int tx = threadIdx.x & 31, ty = threadIdx.x >> 5;
#pragma unroll
    for (int rr = 0; rr < 32; rr += 8)
        t[ty + rr][tx] = W[(size_t)(i0 + ty + rr) * D_ + j0 + tx];
    __syncthreads();
#pragma unroll
    for (int rr = 0; rr < 32; rr += 8)
        Wt[(size_t)(j0 + ty + rr) * D_ + i0 + tx] = (__bf16)t[tx][ty + rr];
}

// ---------------- shared GEMM body (bf16 out, optional scale) ----------------
// R9 structure (best measured: qkv 67.5us / 763 TF). 128x128 tile, BK=32,
// 2 barriers/K-step; ~2-3 resident blocks/CU provide the TLP that covers the
// barrier drain (m114 mechanism). R10-R12 restructures (dbuf, 256-tiles,
// counted vmcnt at 1 block/CU) all measured worse -- do not restructure.
// LDS k-chunk XOR-swizzle by (row>>1)&3: fragment ds_read_b128 conflict-free.
// vperm=1: swap 8B halves of each 16B output chunk for rows with bit3 set;
// consumed by k_attn's V-read (verified R7: attn bank conflicts 4.3M -> 0).
__device__ __forceinline__ void gemm_body_bf16(const __bf16* __restrict__ A,
                                               const __bf16* __restrict__ Bt,
                                               __bf16* __restrict__ C,
                                               int N, int K, int tm, int tn,
                                               float scale, int vperm,
                                               __bf16* As, __bf16* Bs) {
    const int tid  = threadIdx.x;
    const int wave = tid >> 6, lane = tid & 63;
    const int quad = lane >> 4, l16 = lane & 15;
    const int wm = (wave & 1) * 64, wn = (wave >> 1) * 64;
    f32x4 acc[4][4] = {};

    for (int k0 = 0; k0 < K; k0 += 32) {
        __syncthreads();
#pragma unroll
        for (int s = 0; s < 2; s++) {
            const int cb = s * 256 + wave * 64;
            const int c  = cb + lane;
            const int row = c >> 2;
            const int kc  = ((c & 3) ^ ((row >> 1) & 3)) * 8;  // swizzled k-chunk
            __builtin_amdgcn_global_load_lds(GPTR(A + (size_t)(tm + row) * K + k0 + kc),
                                             LPTR(As + cb * 8), 16, 0, 0);
            __builtin_amdgcn_global_load_lds(GPTR(Bt + (size_t)(tn + row) * K + k0 + kc),
                                             LPTR(Bs + cb * 8), 16, 0, 0);
        }
        __syncthreads();

        bf16x8 af[4], bf[4];
#pragma unroll
        for (int mi = 0; mi < 4; mi++) {
            const int rf = wm + mi * 16 + l16;
            af[mi] = *(const bf16x8*)&As[rf * 32 + (quad ^ ((rf >> 1) & 3)) * 8];
        }
#pragma unroll
        for (int ni = 0; ni < 4; ni++) {
            const int rf = wn + ni * 16 + l16;
            bf[ni] = *(const bf16x8*)&Bs[rf * 32 + (quad ^ ((rf >> 1) & 3)) * 8];
        }
#pragma unroll
        for (int mi = 0; mi < 4; mi++)
#pragma unroll
            for (int ni = 0; ni < 4; ni++)
                acc[mi][ni] = __builtin_amdgcn_mfma_f32_16x16x32_bf16(
                    af[mi], bf[ni], acc[mi][ni], 0, 0, 0);
    }

#pragma unroll
    for (int mi = 0; mi < 4; mi++)
#pragma unroll
        for (int ni = 0; ni < 4; ni++)
#pragma unroll
            for (int r = 0; r < 4; r++) {
                const int row = tm + wm + mi * 16 + quad * 4 + r;
                const int col = tn + wn + ni * 16 + l16;
                const int xr  = (vperm & (row >> 3) & 1) << 2;
                C[(size_t)row * N + (col ^ xr)] = (__bf16)(acc[mi][ni][r] * scale);
            }
}

// ---------------- fused QKV projection ----------------
// qk branch: tm-fastest (stride-64 ids share an A-panel -> same XCD under
// round-robin, 64%8==0). VT branch: tn-fastest so each XCD's residue class
// covers only 8 xb token-panels (2MB, L2-fits) — verified R9: FETCH 91->41MB.
__global__ __launch_bounds__(256) void k_gemm_qkv(const __bf16* __restrict__ xb,
                                                  const __bf16* __restrict__ wqkt,
                                                  const __bf16* __restrict__ wvt,
                                                  __bf16* __restrict__ qk,
                                                  __bf16* __restrict__ VT) {
    __shared__ __bf16 As[128 * 32];
    __shared__ __bf16 Bs[128 * 32];
    const int bx = blockIdx.x;
    if (bx < 1024) {
        const int tm = (bx & 63) * 128, tn = (bx >> 6) * 128;
        const float scale = (tn < D_) ? QSCALE : 1.0f;
        gemm_body_bf16(xb, wqkt, qk, QKS, D_, tm, tn, scale, 0, As, Bs);
    } else {
        const int b2 = bx - 1024;
        const int tn = (b2 & 63) * 128, tm = (b2 >> 6) * 128;
        gemm_body_bf16(wvt, xb, VT, NTOK, D_, tm, tn, 1.0f, 1, As, Bs);
    }
}

// ---------------- output GEMM: out = ctx Wo + bo (fp32 epilogue) ----------------
__global__ __launch_bounds__(256) void k_gemm_o(const __bf16* __restrict__ A,
                                                const __bf16* __restrict__ Bt,
                                                float* __restrict__ C,
                                                const float* __restrict__ bias) {
    __shared__ __bf16 As[128 * 32];
    __shared__ __bf16 Bs[128 * 32];
    const int tid  = threadIdx.x;
    const int wave = tid >> 6, lane = tid & 63;
    const int quad = lane >> 4, l16 = lane & 15;
    const int tm = blockIdx.x * 128, tn = blockIdx.y * 128;
    const int wm = (wave & 1) * 64, wn = (wave >> 1) * 64;
    const int N = D_, K = D_;
    f32x4 acc[4][4] = {};

    for (int k0 = 0; k0 < K; k0 += 32) {
        __syncthreads();
#pragma unroll
        for (int s = 0; s < 2; s++) {
            const int cb = s * 256 + wave * 64;
            const int c  = cb + lane;
            const int row = c >> 2;
            const int kc  = ((c & 3) ^ ((row >> 1) & 3)) * 8;  // swizzled k-chunk
            __builtin_amdgcn_global_load_lds(GPTR(A + (size_t)(tm + row) * K + k0 + kc),
                                             LPTR(As + cb * 8), 16, 0, 0);
            __builtin_amdgcn_global_load_lds(GPTR(Bt + (size_t)(tn + row) * K + k0 + kc),
                                             LPTR(Bs + cb * 8), 16, 0, 0);
        }
        __syncthreads();

        bf16x8 af[4], bf[4];
#pragma unroll
        for (int mi = 0; mi < 4; mi++) {
            const int rf = wm + mi * 16 + l16;
            af[mi] = *(const bf16x8*)&As[rf * 32 + (quad ^ ((rf >> 1) & 3)) * 8];
        }
#pragma unroll
        for (int ni = 0; ni < 4; ni++) {
            const int rf = wn + ni * 16 + l16;
            bf[ni] = *(const bf16x8*)&Bs[rf * 32 + (quad ^ ((rf >> 1) & 3)) * 8];
        }
#pragma unroll
        for (int mi = 0; mi < 4; mi++)
#pragma unroll
            for (int ni = 0; ni < 4; ni++)
                acc[mi][ni] = __builtin_amdgcn_mfma_f32_16x16x32_bf16(
                    af[mi], bf[ni], acc[mi][ni], 0, 0, 0);
    }

#pragma unroll
    for (int mi = 0; mi < 4; mi++)
#pragma unroll
        for (int ni = 0; ni < 4; ni++)
#pragma unroll
            for (int r = 0; r < 4; r++) {
                const int row = tm + wm + mi * 16 + quad * 4 + r;
                const int col = tn + wn + ni * 16 + l16;
                C[(size_t)row * N + col] = acc[mi][ni][r] + bias[col];
            }
}

__device__ __forceinline__ short bf16_bits(float f) {
    __bf16 h = (__bf16)f;
    return __builtin_bit_cast(short, h);
}

// ---------------- causal flash attention ----------------
// R9 structure: XCD-aware grouping. bid = g*64 + qp*8 + r, (h,b) = g*8+r ->
// all 8 qp-blocks sharing one (h,b)'s K/V stream on one XCD's L2. Two-pass
// qt pairing (qp, 15-qp) -> uniform 34 k-iters/block. Conflict-free V path:
// vperm'd VT producer + (l16>>3) XOR on half-select (R7: 4.3M -> 0).
// R13: + T5 s_setprio(1) around both MFMA clusters. Regime matches m191's
// verified +4-7%: independent blocks at different phases on one CU (NOT the
// barrier-lockstep GEMM case m190 where it's null).
__global__ __launch_bounds__(256, 2) void k_attn(const __bf16* __restrict__ Qb,
                                                 const __bf16* __restrict__ Kb,
                                                 const __bf16* __restrict__ VT,
                                                 __bf16* __restrict__ ctx) {
    __shared__ __bf16 Ks[2][64 * 64];   // [kv][hd], 16B-chunk XOR-swizzled
    __shared__ __bf16 Vs[2][64 * 64];   // [hd][kv], 16B-chunk XOR-swizzled (+vperm)

    const int tid = threadIdx.x;
    const int wave = tid >> 6, lane = tid & 63;
    const int quad = lane >> 4, l16 = lane & 15;
    const int bid = blockIdx.x;
    const int hb  = ((bid >> 6) << 3) | (bid & 7);   // (h,b) group, fixed per XCD residue
    const int qp  = (bid >> 3) & 7;                  // q-pair index within the group
    const int h = hb >> 2, b = hb & 3;
    const size_t tok0 = (size_t)b * S_;
    const size_t hoff = (size_t)h * HD_;

    auto stage = [&](int kv, int buf) {
#pragma unroll
        for (int s = 0; s < 2; s++) {
            const int cb = s * 256 + wave * 64;
            const int c  = cb + lane;
            const int row = c >> 3;
            const int gc  = (c & 7) ^ (row & 7);
            __builtin_amdgcn_global_load_lds(
                GPTR(Kb + (size_t)(tok0 + kv + row) * QKS + hoff + gc * 8),
                LPTR(&Ks[buf][cb * 8]), 16, 0, 0);
            __builtin_amdgcn_global_load_lds(
                GPTR(VT + (hoff + row) * (size_t)NTOK + tok0 + kv + gc * 8),
                LPTR(&Vs[buf][cb * 8]), 16, 0, 0);
        }
    };

#pragma unroll 1
    for (int sidx = 0; sidx < 2; sidx++) {
        const int qt = sidx == 0 ? qp : 15 - qp;
        const int qb = qt * 128;
        const int q0 = qb + wave * 32;

        // Q as B-operand: B[k=hd=quad*8+j][n=q=l16]
        bf16x8 qf[2][2];
#pragma unroll
        for (int qi = 0; qi < 2; qi++)
#pragma unroll
            for (int ks = 0; ks < 2; ks++)
                qf[qi][ks] = *(const bf16x8*)&Qb[(tok0 + q0 + qi * 16 + l16) * QKS +
                                                 hoff + ks * 32 + quad * 8];

        f32x4 oacc[2][4] = {};     // O^T[hd = hs*16+quad*4+r][q = qi*16+l16]
        float lsum[2] = {0.f, 0.f};
        const int ktb = (qb + 127) >> 6;

        stage(0, 0);
        __syncthreads();

        for (int kt = 0; kt <= ktb; kt++) {
            const int cur = kt & 1;
            const int kv0 = kt * 64;
            if (kt < ktb) stage(kv0 + 64, 1 - cur);   // prefetch overlaps compute

            if (kv0 <= q0 + 31) {
                // S^T = K(A) · Q(B)
                f32x4 st[2][4] = {};
                __builtin_amdgcn_s_setprio(1);
#pragma unroll
                for (int ks = 0; ks < 2; ks++)
#pragma unroll
                    for (int ksub = 0; ksub < 4; ksub++) {
                        const int r = ksub * 16 + l16;
                        bf16x8 kf = *(const bf16x8*)
                            &Ks[cur][(r * 8 + (((ks * 4 + quad) ^ (r & 7)))) * 8];
#pragma unroll
                        for (int qi = 0; qi < 2; qi++)
                            st[qi][ksub] = __builtin_amdgcn_mfma_f32_16x16x32_bf16(
                                kf, qf[qi][ks], st[qi][ksub], 0, 0, 0);
                    }
                __builtin_amdgcn_s_setprio(0);
                if (kv0 + 63 > q0) {   // diagonal tiles: causal mask on S^T
#pragma unroll
                    for (int qi = 0; qi < 2; qi++)
#pragma unroll
                        for (int ksub = 0; ksub < 4; ksub++)
#pragma unroll
                            for (int r = 0; r < 4; r++) {
                                const int kg = kv0 + ksub * 16 + quad * 4 + r;
                                const int qg = q0 + qi * 16 + l16;
                                if (kg > qg) st[qi][ksub][r] = -1e30f;
                            }
                }
                // p = exp2(s); pack P^T into B-frags (registers)
                short4v pfrag[2][4];
#pragma unroll
                for (int qi = 0; qi < 2; qi++)
#pragma unroll
                    for (int ksub = 0; ksub < 4; ksub++) {
                        float p0 = __builtin_amdgcn_exp2f(st[qi][ksub][0]);
                        float p1 = __builtin_amdgcn_exp2f(st[qi][ksub][1]);
                        float p2 = __builtin_amdgcn_exp2f(st[qi][ksub][2]);
                        float p3 = __builtin_amdgcn_exp2f(st[qi][ksub][3]);
                        lsum[qi] += (p0 + p1) + (p2 + p3);
                        short4v pf = {bf16_bits(p0), bf16_bits(p1),
                                      bf16_bits(p2), bf16_bits(p3)};
                        pfrag[qi][ksub] = pf;
                    }
                // O^T += V^T(A) · P^T(B), K=16 MFMAs
                __builtin_amdgcn_s_setprio(1);
#pragma unroll
                for (int ksub = 0; ksub < 4; ksub++)
#pragma unroll
                    for (int hs = 0; hs < 4; hs++) {
                        const int row = hs * 16 + l16;
                        const int swz = (ksub * 2 + (quad >> 1)) ^ (row & 7);
                        short4v vf = *(const short4v*)
                            &Vs[cur][row * 64 + swz * 8 + ((quad ^ (l16 >> 3)) & 1) * 4];
#pragma unroll
                        for (int qi = 0; qi < 2; qi++)
                            oacc[qi][hs] = __builtin_amdgcn_mfma_f32_16x16x16bf16_1k(
                                vf, pfrag[qi][ksub], oacc[qi][hs], 0, 0, 0);
                    }
                __builtin_amdgcn_s_setprio(0);
            }
            __syncthreads();
        }

        // l reduce + epilogue (8B stores, r contiguous in hd)
#pragma unroll
        for (int qi = 0; qi < 2; qi++) {
            float v = lsum[qi];
            v += __shfl_xor(v, 16);
            v += __shfl_xor(v, 32);
            const float rl = 1.0f / v;
#pragma unroll
            for (int hs = 0; hs < 4; hs++) {
                bf16x4 o;
#pragma unroll
                for (int r = 0; r < 4; r++) o[r] = (__bf16)(oacc[qi][hs][r] * rl);
                *(bf16x4*)&ctx[(tok0 + q0 + qi * 16 + l16) * D_ + hoff +
                               hs * 16 + quad * 4] = o;
            }
        }
    }
}

// ---------------- launch ----------------
extern "C" void kernel_launch(void* const* d_in, const int* in_sizes, int n_in,
                              void* d_out, int out_size, void* d_ws, size_t ws_size,
                              hipStream_t stream) {
    const float* x  = (const float*)d_in[0];
    const float* Wq = (const float*)d_in[1];
    const float* Wk = (const float*)d_in[2];
    const float* Wv = (const float*)d_in[3];
    const float* Wo = (const float*)d_in[4];
    const float* bo = (const float*)d_in[5];
    float* out = (float*)d_out;

    char* p = (char*)d_ws;
    __bf16* xb   = (__bf16*)p; p += (size_t)NTOK * D_ * 2;   // 16 MB
    __bf16* wqkt = (__bf16*)p; p += (size_t)2 * D_ * D_ * 2; // 4 MB
    __bf16* wvt  = (__bf16*)p; p += (size_t)D_ * D_ * 2;     // 2 MB
    __bf16* wot  = (__bf16*)p; p += (size_t)D_ * D_ * 2;     // 2 MB
    __bf16* qk   = (__bf16*)p; p += (size_t)NTOK * QKS * 2;  // 32 MB [tok][Q|K]
    __bf16* VT   = (__bf16*)p; p += (size_t)NTOK * D_ * 2;   // 16 MB [d][tok]
    __bf16* ctx  = (__bf16*)p; p += (size_t)NTOK * D_ * 2;   // 16 MB

    k_prep<<<dim3(4096 + 4 * 1024), 256, 0, stream>>>(x, xb, Wq, Wk, Wv, Wo,
                                                      wqkt, wvt, wot);
    k_gemm_qkv<<<dim3(1024 + 512), 256, 0, stream>>>(xb, wqkt, wvt, qk, VT);
    k_attn<<<dim3(512), 256, 0, stream>>>(qk, qk + D_, VT, ctx);
    k_gemm_o<<<dim3(64, 8), 256, 0, stream>>>(ctx, wot, out, bo);
}

// Round 8
// 234.665 us; speedup vs baseline: 1.0999x; 1.0148x over previous
//
#include <hip/hip_runtime.h>

#define S_   2048
#define D_   1024
#define H_   16
#define HD_  64
#define NTOK 8192   // B*S
#define QKS  2048   // row stride of fused QK output
#define QSCALE 0.18033688f  // 0.125 * log2(e) — folded into Q at projection time

typedef __attribute__((ext_vector_type(8))) __bf16 bf16x8;
typedef __attribute__((ext_vector_type(4))) __bf16 bf16x4;
typedef __attribute__((ext_vector_type(4))) float  f32x4;
typedef __attribute__((ext_vector_type(4))) short  short4v;

#define GPTR(p) ((__attribute__((address_space(1))) void*)(unsigned long long)(p))
#define LPTR(p) ((__attribute__((address_space(3))) void*)(p))

// ---------------- fused prep: cast x -> bf16, transpose 4 weights ----------------
__global__ __launch_bounds__(256) void k_prep(const float* __restrict__ x,
                                              __bf16* __restrict__ xb,
                                              const float* __restrict__ Wq,
                                              const float* __restrict__ Wk,
                                              const float* __restrict__ Wv,
                                              const float* __restrict__ Wo,
                                              __bf16* __restrict__ wqkt,
                                              __bf16* __restrict__ wvt,
                                              __bf16* __restrict__ wot) {
    const int bx = blockIdx.x;
    if (bx < 4096) {
        int i = bx * 2048 + threadIdx.x * 8;
        f32x4 a = *(const f32x4*)(x + i);
        f32x4 b = *(const f32x4*)(x + i + 4);
        bf16x8 o;
#pragma unroll
        for (int j = 0; j < 4; j++) { o[j] = (__bf16)a[j]; o[4 + j] = (__bf16)b[j]; }
        *(bf16x8*)(xb + i) = o;
        return;
    }
    __shared__ float t[32][33];
    const int tt = bx - 4096;
    const int widx = tt >> 10, r = tt & 1023;
    const float* W;
    __bf16* Wt;
    switch (widx) {
        case 0: W = Wq; Wt = wqkt; break;
        case 1: W = Wk; Wt = wqkt + (size_t)D_ * D_; break;
        case 2: W = Wv; Wt = wvt; break;
        default: W = Wo; Wt = wot; break;
    }
    const int i0 = (r & 31) * 32, j0 = (r >> 5) * 32;
    const int tx = threadIdx.x & 31, ty = threadIdx.x >> 5;
#pragma unroll
    for (int rr = 0; rr < 32; rr += 8)
        t[ty + rr][tx] = W[(size_t)(i0 + ty + rr) * D_ + j0 + tx];
    __syncthreads();
#pragma unroll
    for (int rr = 0; rr < 32; rr += 8)
        Wt[(size_t)(j0 + ty + rr) * D_ + i0 + tx] = (__bf16)t[tx][ty + rr];
}

// ---------------- shared GEMM body (bf16 out, optional scale) ----------------
// R9 structure (best measured: qkv 67.5us / 763 TF). 128x128 tile, BK=32,
// 2 barriers/K-step; ~2-3 resident blocks/CU provide the TLP that covers the
// barrier drain (m114 mechanism). R10-R13 restructures all measured worse --
// do not restructure.
// LDS k-chunk XOR-swizzle by (row>>1)&3: fragment ds_read_b128 conflict-free.
// vperm=1: swap 8B halves of each 16B output chunk for rows with bit3 set;
// consumed by k_attn's V-read (verified R7: attn bank conflicts 4.3M -> 0).
__device__ __forceinline__ void gemm_body_bf16(const __bf16* __restrict__ A,
                                               const __bf16* __restrict__ Bt,
                                               __bf16* __restrict__ C,
                                               int N, int K, int tm, int tn,
                                               float scale, int vperm,
                                               __bf16* As, __bf16* Bs) {
    const int tid  = threadIdx.x;
    const int wave = tid >> 6, lane = tid & 63;
    const int quad = lane >> 4, l16 = lane & 15;
    const int wm = (wave & 1) * 64, wn = (wave >> 1) * 64;
    f32x4 acc[4][4] = {};

    for (int k0 = 0; k0 < K; k0 += 32) {
        __syncthreads();
#pragma unroll
        for (int s = 0; s < 2; s++) {
            const int cb = s * 256 + wave * 64;
            const int c  = cb + lane;
            const int row = c >> 2;
            const int kc  = ((c & 3) ^ ((row >> 1) & 3)) * 8;  // swizzled k-chunk
            __builtin_amdgcn_global_load_lds(GPTR(A + (size_t)(tm + row) * K + k0 + kc),
                                             LPTR(As + cb * 8), 16, 0, 0);
            __builtin_amdgcn_global_load_lds(GPTR(Bt + (size_t)(tn + row) * K + k0 + kc),
                                             LPTR(Bs + cb * 8), 16, 0, 0);
        }
        __syncthreads();

        bf16x8 af[4], bf[4];
#pragma unroll
        for (int mi = 0; mi < 4; mi++) {
            const int rf = wm + mi * 16 + l16;
            af[mi] = *(const bf16x8*)&As[rf * 32 + (quad ^ ((rf >> 1) & 3)) * 8];
        }
#pragma unroll
        for (int ni = 0; ni < 4; ni++) {
            const int rf = wn + ni * 16 + l16;
            bf[ni] = *(const bf16x8*)&Bs[rf * 32 + (quad ^ ((rf >> 1) & 3)) * 8];
        }
#pragma unroll
        for (int mi = 0; mi < 4; mi++)
#pragma unroll
            for (int ni = 0; ni < 4; ni++)
                acc[mi][ni] = __builtin_amdgcn_mfma_f32_16x16x32_bf16(
                    af[mi], bf[ni], acc[mi][ni], 0, 0, 0);
    }

#pragma unroll
    for (int mi = 0; mi < 4; mi++)
#pragma unroll
        for (int ni = 0; ni < 4; ni++)
#pragma unroll
            for (int r = 0; r < 4; r++) {
                const int row = tm + wm + mi * 16 + quad * 4 + r;
                const int col = tn + wn + ni * 16 + l16;
                const int xr  = (vperm & (row >> 3) & 1) << 2;
                C[(size_t)row * N + (col ^ xr)] = (__bf16)(acc[mi][ni][r] * scale);
            }
}

// ---------------- fused QKV projection ----------------
// qk branch: tm-fastest (stride-64 ids share an A-panel -> same XCD under
// round-robin, 64%8==0). VT branch: tn-fastest so each XCD's residue class
// covers only 8 xb token-panels (2MB, L2-fits) — verified R9: FETCH 91->41MB.
__global__ __launch_bounds__(256) void k_gemm_qkv(const __bf16* __restrict__ xb,
                                                  const __bf16* __restrict__ wqkt,
                                                  const __bf16* __restrict__ wvt,
                                                  __bf16* __restrict__ qk,
                                                  __bf16* __restrict__ VT) {
    __shared__ __bf16 As[128 * 32];
    __shared__ __bf16 Bs[128 * 32];
    const int bx = blockIdx.x;
    if (bx < 1024) {
        const int tm = (bx & 63) * 128, tn = (bx >> 6) * 128;
        const float scale = (tn < D_) ? QSCALE : 1.0f;
        gemm_body_bf16(xb, wqkt, qk, QKS, D_, tm, tn, scale, 0, As, Bs);
    } else {
        const int b2 = bx - 1024;
        const int tn = (b2 & 63) * 128, tm = (b2 >> 6) * 128;
        gemm_body_bf16(wvt, xb, VT, NTOK, D_, tm, tn, 1.0f, 1, As, Bs);
    }
}

// ---------------- output GEMM: out = ctx Wo + bo (fp32 epilogue) ----------------
__global__ __launch_bounds__(256) void k_gemm_o(const __bf16* __restrict__ A,
                                                const __bf16* __restrict__ Bt,
                                                float* __restrict__ C,
                                                const float* __restrict__ bias) {
    __shared__ __bf16 As[128 * 32];
    __shared__ __bf16 Bs[128 * 32];
    const int tid  = threadIdx.x;
    const int wave = tid >> 6, lane = tid & 63;
    const int quad = lane >> 4, l16 = lane & 15;
    const int tm = blockIdx.x * 128, tn = blockIdx.y * 128;
    const int wm = (wave & 1) * 64, wn = (wave >> 1) * 64;
    const int N = D_, K = D_;
    f32x4 acc[4][4] = {};

    for (int k0 = 0; k0 < K; k0 += 32) {
        __syncthreads();
#pragma unroll
        for (int s = 0; s < 2; s++) {
            const int cb = s * 256 + wave * 64;
            const int c  = cb + lane;
            const int row = c >> 2;
            const int kc  = ((c & 3) ^ ((row >> 1) & 3)) * 8;  // swizzled k-chunk
            __builtin_amdgcn_global_load_lds(GPTR(A + (size_t)(tm + row) * K + k0 + kc),
                                             LPTR(As + cb * 8), 16, 0, 0);
            __builtin_amdgcn_global_load_lds(GPTR(Bt + (size_t)(tn + row) * K + k0 + kc),
                                             LPTR(Bs + cb * 8), 16, 0, 0);
        }
        __syncthreads();

        bf16x8 af[4], bf[4];
#pragma unroll
        for (int mi = 0; mi < 4; mi++) {
            const int rf = wm + mi * 16 + l16;
            af[mi] = *(const bf16x8*)&As[rf * 32 + (quad ^ ((rf >> 1) & 3)) * 8];
        }
#pragma unroll
        for (int ni = 0; ni < 4; ni++) {
            const int rf = wn + ni * 16 + l16;
            bf[ni] = *(const bf16x8*)&Bs[rf * 32 + (quad ^ ((rf >> 1) & 3)) * 8];
        }
#pragma unroll
        for (int mi = 0; mi < 4; mi++)
#pragma unroll
            for (int ni = 0; ni < 4; ni++)
                acc[mi][ni] = __builtin_amdgcn_mfma_f32_16x16x32_bf16(
                    af[mi], bf[ni], acc[mi][ni], 0, 0, 0);
    }

#pragma unroll
    for (int mi = 0; mi < 4; mi++)
#pragma unroll
        for (int ni = 0; ni < 4; ni++)
#pragma unroll
            for (int r = 0; r < 4; r++) {
                const int row = tm + wm + mi * 16 + quad * 4 + r;
                const int col = tn + wn + ni * 16 + l16;
                C[(size_t)row * N + col] = acc[mi][ni][r] + bias[col];
            }
}

__device__ __forceinline__ short bf16_bits(float f) {
    __bf16 h = (__bf16)f;
    return __builtin_bit_cast(short, h);
}

// ---------------- causal flash attention ----------------
// R14: 64-row chunk pairs -> 4 blocks/CU all-resident, uniform work.
// bid -> hb = (bid>>7)*8 + (bid&7) (same-hb blocks share an XCD: bid&7),
// qp = (bid>>3)&15. Block processes 64-row chunk 31-qp then chunk qp:
// iters = (32-qp) + (qp+1) = 33 for EVERY block -> all 1024 blocks resident
// (4/CU, 128KB LDS, 16 waves/CU) and all finish together (no tail, no
// imbalance -- the two diagnosed R7 failure causes). Attacks the measured
// occupancy limit (18.5% = grid-capped 2 blocks/CU; MFMA 30 / VALU 35 both
// unsaturated = barrier-latency-bound). Per-wave state halves (16 q-rows).
// Conflict-free V path unchanged: vperm'd VT producer + (l16>>3) XOR
// half-select (R7: bank conflicts 4.3M -> 0). No setprio (R13: -4us).
__global__ __launch_bounds__(256, 4) void k_attn(const __bf16* __restrict__ Qb,
                                                 const __bf16* __restrict__ Kb,
                                                 const __bf16* __restrict__ VT,
                                                 __bf16* __restrict__ ctx) {
    __shared__ __bf16 Ks[2][64 * 64];   // [kv][hd], 16B-chunk XOR-swizzled
    __shared__ __bf16 Vs[2][64 * 64];   // [hd][kv], 16B-chunk XOR-swizzled (+vperm)

    const int tid = threadIdx.x;
    const int wave = tid >> 6, lane = tid & 63;
    const int quad = lane >> 4, l16 = lane & 15;
    const int bid = blockIdx.x;
    const int hb  = ((bid >> 7) << 3) | (bid & 7);   // (h,b), fixed per XCD residue
    const int qp  = (bid >> 3) & 15;                 // chunk-pair index
    const int h = hb >> 2, b = hb & 3;
    const size_t tok0 = (size_t)b * S_;
    const size_t hoff = (size_t)h * HD_;

    auto stage = [&](int kv, int buf) {
#pragma unroll
        for (int s = 0; s < 2; s++) {
            const int cb = s * 256 + wave * 64;
            const int c  = cb + lane;
            const int row = c >> 3;
            const int gc  = (c & 7) ^ (row & 7);
            __builtin_amdgcn_global_load_lds(
                GPTR(Kb + (size_t)(tok0 + kv + row) * QKS + hoff + gc * 8),
                LPTR(&Ks[buf][cb * 8]), 16, 0, 0);
            __builtin_amdgcn_global_load_lds(
                GPTR(VT + (hoff + row) * (size_t)NTOK + tok0 + kv + gc * 8),
                LPTR(&Vs[buf][cb * 8]), 16, 0, 0);
        }
    };

#pragma unroll 1
    for (int pass = 0; pass < 2; pass++) {
        const int j  = pass == 0 ? 31 - qp : qp;   // 64-row chunk index (long first)
        const int qb = j * 64;
        const int q0 = qb + wave * 16;             // 16 q-rows per wave

        // Q as B-operand: B[k=hd=quad*8+jj][n=q=l16]
        bf16x8 qf[2];
#pragma unroll
        for (int ks = 0; ks < 2; ks++)
            qf[ks] = *(const bf16x8*)&Qb[(tok0 + q0 + l16) * QKS +
                                         hoff + ks * 32 + quad * 8];

        f32x4 oacc[4] = {};     // O^T[hd = hs*16+quad*4+r][q = l16]
        float lsum = 0.f;
        const int ktb = j;      // (qb+63)>>6

        stage(0, 0);
        __syncthreads();

        for (int kt = 0; kt <= ktb; kt++) {
            const int cur = kt & 1;
            const int kv0 = kt * 64;
            if (kt < ktb) stage(kv0 + 64, 1 - cur);   // prefetch overlaps compute

            if (kv0 <= q0 + 15) {
                // S^T = K(A) · Q(B)
                f32x4 st[4] = {};
#pragma unroll
                for (int ks = 0; ks < 2; ks++)
#pragma unroll
                    for (int ksub = 0; ksub < 4; ksub++) {
                        const int r = ksub * 16 + l16;
                        bf16x8 kf = *(const bf16x8*)
                            &Ks[cur][(r * 8 + (((ks * 4 + quad) ^ (r & 7)))) * 8];
                        st[ksub] = __builtin_amdgcn_mfma_f32_16x16x32_bf16(
                            kf, qf[ks], st[ksub], 0, 0, 0);
                    }
                if (kv0 + 63 > q0) {   // diagonal tiles: causal mask on S^T
#pragma unroll
                    for (int ksub = 0; ksub < 4; ksub++)
#pragma unroll
                        for (int r = 0; r < 4; r++) {
                            const int kg = kv0 + ksub * 16 + quad * 4 + r;
                            const int qg = q0 + l16;
                            if (kg > qg) st[ksub][r] = -1e30f;
                        }
                }
                // p = exp2(s); pack P^T into B-frags (registers)
                short4v pfrag[4];
#pragma unroll
                for (int ksub = 0; ksub < 4; ksub++) {
                    float p0 = __builtin_amdgcn_exp2f(st[ksub][0]);
                    float p1 = __builtin_amdgcn_exp2f(st[ksub][1]);
                    float p2 = __builtin_amdgcn_exp2f(st[ksub][2]);
                    float p3 = __builtin_amdgcn_exp2f(st[ksub][3]);
                    lsum += (p0 + p1) + (p2 + p3);
                    short4v pf = {bf16_bits(p0), bf16_bits(p1),
                                  bf16_bits(p2), bf16_bits(p3)};
                    pfrag[ksub] = pf;
                }
                // O^T += V^T(A) · P^T(B), K=16 MFMAs
#pragma unroll
                for (int ksub = 0; ksub < 4; ksub++)
#pragma unroll
                    for (int hs = 0; hs < 4; hs++) {
                        const int row = hs * 16 + l16;
                        const int swz = (ksub * 2 + (quad >> 1)) ^ (row & 7);
                        short4v vf = *(const short4v*)
                            &Vs[cur][row * 64 + swz * 8 + ((quad ^ (l16 >> 3)) & 1) * 4];
                        oacc[hs] = __builtin_amdgcn_mfma_f32_16x16x16bf16_1k(
                            vf, pfrag[ksub], oacc[hs], 0, 0, 0);
                    }
            }
            __syncthreads();
        }

        // l reduce + epilogue (8B stores, r contiguous in hd)
        {
            float v = lsum;
            v += __shfl_xor(v, 16);
            v += __shfl_xor(v, 32);
            const float rl = 1.0f / v;
#pragma unroll
            for (int hs = 0; hs < 4; hs++) {
                bf16x4 o;
#pragma unroll
                for (int r = 0; r < 4; r++) o[r] = (__bf16)(oacc[hs][r] * rl);
                *(bf16x4*)&ctx[(tok0 + q0 + l16) * D_ + hoff +
                               hs * 16 + quad * 4] = o;
            }
        }
    }
}

// ---------------- launch ----------------
extern "C" void kernel_launch(void* const* d_in, const int* in_sizes, int n_in,
                              void* d_out, int out_size, void* d_ws, size_t ws_size,
                              hipStream_t stream) {
    const float* x  = (const float*)d_in[0];
    const float* Wq = (const float*)d_in[1];
    const float* Wk = (const float*)d_in[2];
    const float* Wv = (const float*)d_in[3];
    const float* Wo = (const float*)d_in[4];
    const float* bo = (const float*)d_in[5];
    float* out = (float*)d_out;

    char* p = (char*)d_ws;
    __bf16* xb   = (__bf16*)p; p += (size_t)NTOK * D_ * 2;   // 16 MB
    __bf16* wqkt = (__bf16*)p; p += (size_t)2 * D_ * D_ * 2; // 4 MB
    __bf16* wvt  = (__bf16*)p; p += (size_t)D_ * D_ * 2;     // 2 MB
    __bf16* wot  = (__bf16*)p; p += (size_t)D_ * D_ * 2;     // 2 MB
    __bf16* qk   = (__bf16*)p; p += (size_t)NTOK * QKS * 2;  // 32 MB [tok][Q|K]
    __bf16* VT   = (__bf16*)p; p += (size_t)NTOK * D_ * 2;   // 16 MB [d][tok]
    __bf16* ctx  = (__bf16*)p; p += (size_t)NTOK * D_ * 2;   // 16 MB

    k_prep<<<dim3(4096 + 4 * 1024), 256, 0, stream>>>(x, xb, Wq, Wk, Wv, Wo,
                                                      wqkt, wvt, wot);
    k_gemm_qkv<<<dim3(1024 + 512), 256, 0, stream>>>(xb, wqkt, wvt, qk, VT);
    k_attn<<<dim3(1024), 256, 0, stream>>>(qk, qk + D_, VT, ctx);
    k_gemm_o<<<dim3(64, 8), 256, 0, stream>>>(ctx, wot, out, bo);
}